// Round 1
// baseline (110.383 us; speedup 1.0000x reference)
//
#include <hip/hip_runtime.h>
#include <stdint.h>

#define NB 16
#define CC 32
#define HH 224
#define WWID 224
#define HWS (HH*WWID)          // 50176
#define NHWT (NB*HWS)          // 802816
#define TOT (NB*CC*HWS)        // 25690112

// ---------- pack weights: (32,32,3,3) fp32 -> 288 x {signbits, nzbits} ----------
__global__ void pack_w(const float* __restrict__ w, uint2* __restrict__ wp) {
    int k = threadIdx.x;               // co*9 + tap
    if (k >= CC * 9) return;
    int co = k / 9, tap = k % 9;
    unsigned bits = 0, nz = 0;
    for (int ci = 0; ci < CC; ++ci) {
        float v = w[(co * CC + ci) * 9 + tap];
        bits |= (v > 0.f ? 1u : 0u) << ci;
        nz   |= (v != 0.f ? 1u : 0u) << ci;
    }
    wp[k] = make_uint2(bits, nz);
}

// ---------- pack x: NCHW fp32 -> per-(n,h,w) {signbits, nzbits} over c ----------
__global__ void __launch_bounds__(256) pack_x(const float* __restrict__ x,
                                              uint2* __restrict__ xp) {
    int p = blockIdx.x * 256 + threadIdx.x;   // n*HWS + hw
    int n = p / HWS, hw = p % HWS;
    const float* base = x + (size_t)n * CC * HWS + hw;
    unsigned bits = 0, nz = 0;
    #pragma unroll
    for (int c = 0; c < CC; ++c) {
        float v = base[(size_t)c * HWS];
        bits |= (v > 0.f ? 1u : 0u) << c;
        nz   |= (v != 0.f ? 1u : 0u) << c;
    }
    xp[p] = make_uint2(bits, nz);
}

// ---------- binary conv 3x3 pad 1: popcount form, exact ints -> int16 ----------
__global__ void __launch_bounds__(256) bconv(const uint2* __restrict__ xp,
                                             const uint2* __restrict__ wp,
                                             short* __restrict__ y) {
    __shared__ uint2 wl[CC * 9];
    for (int i = threadIdx.x; i < CC * 9; i += 256) wl[i] = wp[i];
    __syncthreads();

    int p = blockIdx.x * 256 + threadIdx.x;
    int n = p / HWS, hw = p % HWS;
    int h = hw / WWID, w = hw % WWID;

    unsigned xb[9], xn[9];
    #pragma unroll
    for (int dh = -1; dh <= 1; ++dh) {
        #pragma unroll
        for (int dw = -1; dw <= 1; ++dw) {
            int k = (dh + 1) * 3 + (dw + 1);
            int hh = h + dh, ww = w + dw;
            bool ok = ((unsigned)hh < (unsigned)HH) && ((unsigned)ww < (unsigned)WWID);
            uint2 v = make_uint2(0u, 0u);
            if (ok) v = xp[n * HWS + hh * WWID + ww];
            xb[k] = v.x; xn[k] = v.y;
        }
    }

    short* yo = y + (size_t)n * CC * HWS + hw;
    for (int co = 0; co < CC; ++co) {
        int am = 0, ad = 0;
        #pragma unroll
        for (int k = 0; k < 9; ++k) {
            uint2 q = wl[co * 9 + k];
            unsigned m = xn[k] & q.y;
            am += __popc(m);
            ad += __popc((xb[k] ^ q.x) & m);
        }
        yo[(size_t)co * HWS] = (short)(am - 2 * ad);
    }
}

// ---------- per-channel exact integer stats: one block per (n,c) plane ----------
__global__ void __launch_bounds__(256) bstats(const short* __restrict__ y,
                                              int* __restrict__ s_sum,
                                              unsigned long long* __restrict__ s_sq) {
    int plane = blockIdx.x;            // n*32 + c
    int c = plane & 31;
    const short4* base = (const short4*)(y + (size_t)plane * HWS);
    int sum = 0, sq = 0;               // per-thread: <= 196*288 and 196*288^2, fit int32
    #pragma unroll 7
    for (int j = 0; j < 49; ++j) {     // 49 * 256 * 4 = 50176
        short4 v = base[j * 256 + threadIdx.x];
        int a = v.x, b = v.y, cc = v.z, d = v.w;
        sum += a + b + cc + d;
        sq  += a * a + b * b + cc * cc + d * d;
    }
    long long sql = sq;
    for (int off = 32; off; off >>= 1) {
        sum += __shfl_down(sum, off);
        sql += __shfl_down(sql, off);
    }
    __shared__ int wsum[4];
    __shared__ long long wsq[4];
    int wid = threadIdx.x >> 6, lane = threadIdx.x & 63;
    if (lane == 0) { wsum[wid] = sum; wsq[wid] = sql; }
    __syncthreads();
    if (threadIdx.x == 0) {
        int S = 0; long long Q = 0;
        for (int i = 0; i < 4; ++i) { S += wsum[i]; Q += wsq[i]; }
        atomicAdd(&s_sum[c], S);
        atomicAdd(&s_sq[c], (unsigned long long)Q);
    }
}

// ---------- finalize BN: scale/shift per channel ----------
__global__ void bfinal(const int* __restrict__ s_sum,
                       const unsigned long long* __restrict__ s_sq,
                       const float* __restrict__ gamma, const float* __restrict__ beta,
                       float* __restrict__ scale, float* __restrict__ shift) {
    int c = threadIdx.x;
    if (c >= CC) return;
    double mean = (double)s_sum[c] / (double)NHWT;
    double var  = (double)(long long)s_sq[c] / (double)NHWT - mean * mean;
    float inv = (float)(1.0 / sqrt(var + 1e-5));
    float g = gamma[c] * inv;
    scale[c] = g;
    shift[c] = beta[c] - (float)mean * g;
}

// ---------- normalize: out = y*scale[c] + shift[c] ----------
__global__ void __launch_bounds__(256) bnorm(const short* __restrict__ y,
                                             const float* __restrict__ scale,
                                             const float* __restrict__ shift,
                                             float* __restrict__ out) {
    int t = blockIdx.x * 256 + threadIdx.x;
    int i = t * 8;                        // 8 elems per thread; 50176 % 8 == 0
    int c = (i / HWS) & 31;
    float s = scale[c], b = shift[c];
    const short4* yv = (const short4*)y;
    short4 v0 = yv[2 * t], v1 = yv[2 * t + 1];
    float4* ov = (float4*)out;
    ov[2 * t]     = make_float4(v0.x * s + b, v0.y * s + b, v0.z * s + b, v0.w * s + b);
    ov[2 * t + 1] = make_float4(v1.x * s + b, v1.y * s + b, v1.z * s + b, v1.w * s + b);
}

extern "C" void kernel_launch(void* const* d_in, const int* in_sizes, int n_in,
                              void* d_out, int out_size, void* d_ws, size_t ws_size,
                              hipStream_t stream) {
    const float* x     = (const float*)d_in[0];
    const float* w     = (const float*)d_in[1];
    const float* gamma = (const float*)d_in[2];
    const float* beta  = (const float*)d_in[3];
    float* out = (float*)d_out;

    char* ws = (char*)d_ws;
    uint2* wpk                  = (uint2*)(ws);                 // 2304 B
    int* s_sum                  = (int*)(ws + 4096);            // 128 B
    unsigned long long* s_sq    = (unsigned long long*)(ws + 4352); // 256 B
    float* scale                = (float*)(ws + 4608);          // 128 B
    float* shift                = (float*)(ws + 4736);          // 128 B
    uint2* xpk                  = (uint2*)(ws + 8192);          // 802816*8 = 6,422,528 B
    short* y16                  = (short*)(ws + 8192 + (size_t)NHWT * 8); // 51,380,224 B

    // zero the atomic accumulators every launch (ws is not re-poisoned between replays)
    hipMemsetAsync(ws + 4096, 0, 768, stream);

    pack_w<<<1, 320, 0, stream>>>(w, wpk);
    pack_x<<<NHWT / 256, 256, 0, stream>>>(x, xpk);
    bconv<<<NHWT / 256, 256, 0, stream>>>(xpk, wpk, y16);
    bstats<<<NB * CC, 256, 0, stream>>>(y16, s_sum, s_sq);
    bfinal<<<1, 64, 0, stream>>>(s_sum, s_sq, gamma, beta, scale, shift);
    bnorm<<<TOT / 2048, 256, 0, stream>>>(y16, scale, shift, out);
}